// Round 1
// baseline (520.409 us; speedup 1.0000x reference)
//
#include <hip/hip_runtime.h>

// Problem constants (B=4, S=2048, E=1024, H=16, D=64)
#define BATCH 4
#define SLEN  2048
#define EDIM  1024
#define NHEAD 16
#define DHEAD 64
#define MTOT  (BATCH * SLEN)   // 8192 rows

typedef float f32x4 __attribute__((ext_vector_type(4)));
typedef __bf16 bf16x8 __attribute__((ext_vector_type(8)));
typedef unsigned short u16x8 __attribute__((ext_vector_type(8)));

__device__ __forceinline__ unsigned short f32_to_bf16(float f) {
    unsigned int u = __float_as_uint(f);
    u = (u + 0x7FFFu + ((u >> 16) & 1u)) >> 16;
    return (unsigned short)u;
}

__device__ __forceinline__ void gload_lds16(const void* g, void* l) {
    __builtin_amdgcn_global_load_lds(
        (const __attribute__((address_space(1))) void*)g,
        (__attribute__((address_space(3))) void*)l, 16, 0, 0);
}

// ---------------- fp32 -> bf16 cast ----------------
__global__ void cast_f32_bf16(const float* __restrict__ src,
                              unsigned short* __restrict__ dst, int n) {
    int idx = (blockIdx.x * blockDim.x + threadIdx.x) * 4;
    if (idx < n) {
        float4 f = *(const float4*)(src + idx);
        ushort4 o;
        o.x = f32_to_bf16(f.x); o.y = f32_to_bf16(f.y);
        o.z = f32_to_bf16(f.z); o.w = f32_to_bf16(f.w);
        *(ushort4*)(dst + idx) = o;
    }
}

// ---------------- C = A * B^T (A[M,K], B[N,K] row-major, bf16 in, fp32 acc) ----
// m97 structure: 128x128 tile, BK=32, 4 waves each computing 64x64.
template <typename OutT>
__global__ __launch_bounds__(256) void gemm_bt(
    const unsigned short* __restrict__ A,   // [M,K] bf16
    const unsigned short* __restrict__ Bm,  // [N,K] bf16
    OutT* __restrict__ C,                   // [M,N]
    int M, int N, int K)
{
    __shared__ unsigned short As[128 * 32];
    __shared__ unsigned short Bs[128 * 32];

    const int bm = blockIdx.x;
    const int bn = blockIdx.y;
    const int tid = threadIdx.x;
    const int wave = tid >> 6, lane = tid & 63;
    const int quad = lane >> 4, l16 = lane & 15;
    const int wm = (wave >> 1) * 64, wn = (wave & 1) * 64;

    f32x4 acc[4][4];
    const f32x4 zero = {0.f, 0.f, 0.f, 0.f};
    #pragma unroll
    for (int i = 0; i < 4; ++i)
        #pragma unroll
        for (int j = 0; j < 4; ++j) acc[i][j] = zero;

    for (int k0 = 0; k0 < K; k0 += 32) {
        #pragma unroll
        for (int c = 0; c < 2; ++c) {
            int flat = c * 2048 + tid * 8;
            int row = flat >> 5, col = flat & 31;
            gload_lds16(A + (size_t)(bm * 128 + row) * K + k0 + col, As + flat);
            gload_lds16(Bm + (size_t)(bn * 128 + row) * K + k0 + col, Bs + flat);
        }
        __syncthreads();

        bf16x8 a_frag[4], b_frag[4];
        #pragma unroll
        for (int i = 0; i < 4; ++i) {
            a_frag[i] = *(const bf16x8*)(As + (wm + i * 16 + l16) * 32 + quad * 8);
            b_frag[i] = *(const bf16x8*)(Bs + (wn + i * 16 + l16) * 32 + quad * 8);
        }
        #pragma unroll
        for (int i = 0; i < 4; ++i)
            #pragma unroll
            for (int j = 0; j < 4; ++j)
                acc[i][j] = __builtin_amdgcn_mfma_f32_16x16x32_bf16(
                    a_frag[i], b_frag[j], acc[i][j], 0, 0, 0);
        __syncthreads();
    }

    // Epilogue: C/D layout col = lane&15, row = quad*4 + reg
    #pragma unroll
    for (int i = 0; i < 4; ++i) {
        int row = bm * 128 + wm + i * 16 + quad * 4;
        #pragma unroll
        for (int j = 0; j < 4; ++j) {
            int col = bn * 128 + wn + j * 16 + l16;
            #pragma unroll
            for (int r = 0; r < 4; ++r) {
                float v = acc[i][j][r];
                if constexpr (sizeof(OutT) == 2)
                    ((unsigned short*)C)[(size_t)(row + r) * N + col] = f32_to_bf16(v);
                else
                    ((float*)C)[(size_t)(row + r) * N + col] = v;
            }
        }
    }
}

// ---------------- flash causal attention ----------------
// grid = (S/64, H, B); block = 256 (4 waves). Each block: 64 q rows of one head.
// Wave w owns q rows [w*16, w*16+16).
__global__ __launch_bounds__(256) void flash_attn(
    const unsigned short* __restrict__ Q,  // [B,S,E] bf16
    const unsigned short* __restrict__ K,
    const unsigned short* __restrict__ V,
    unsigned short* __restrict__ O)        // [B,S,E] bf16
{
    const int qt = blockIdx.x;
    const int h  = blockIdx.y;
    const int b  = blockIdx.z;
    const int tid = threadIdx.x;
    const int wave = tid >> 6, lane = tid & 63;
    const int quad = lane >> 4, l16 = lane & 15;

    __shared__ unsigned short Ks[64 * 64];   // [key][dim]
    __shared__ unsigned short Vst[64 * 72];  // [dim][key], padded stride 72
    __shared__ unsigned short Ps[64 * 72];   // [qrow][key], padded stride 72

    const size_t base = (size_t)b * SLEN * EDIM + (size_t)h * DHEAD;

    // Q fragments (A-operand): A[m=l16][k = s*32 + quad*8 + j]
    bf16x8 q_frag[2];
    {
        const unsigned short* qp =
            Q + base + (size_t)(qt * 64 + wave * 16 + l16) * EDIM + quad * 8;
        q_frag[0] = *(const bf16x8*)(qp);
        q_frag[1] = *(const bf16x8*)(qp + 32);
    }

    const f32x4 zero = {0.f, 0.f, 0.f, 0.f};
    f32x4 o_acc[4];
    #pragma unroll
    for (int j = 0; j < 4; ++j) o_acc[j] = zero;
    float m_r[4], l_r[4];
    #pragma unroll
    for (int r = 0; r < 4; ++r) { m_r[r] = -INFINITY; l_r[r] = 0.f; }

    for (int kt = 0; kt <= qt; ++kt) {
        // stage K tile [64 keys][64 dims] via global_load_lds
        #pragma unroll
        for (int c = 0; c < 2; ++c) {
            int flat = c * 2048 + tid * 8;
            int row = flat >> 6, col = flat & 63;
            gload_lds16(K + base + (size_t)(kt * 64 + row) * EDIM + col, Ks + flat);
        }
        // stage V transposed: Vst[dim][key]
        {
            int r = tid >> 2;
            int cb = (tid & 3) * 16;
            const unsigned short* g = V + base + (size_t)(kt * 64 + r) * EDIM + cb;
            u16x8 v0 = *(const u16x8*)(g);
            u16x8 v1 = *(const u16x8*)(g + 8);
            #pragma unroll
            for (int j = 0; j < 8; ++j) {
                Vst[(cb + j) * 72 + r] = v0[j];
                Vst[(cb + 8 + j) * 72 + r] = v1[j];
            }
        }
        __syncthreads();

        // S = Q K^T for this wave's 16 rows (N = 64 keys -> 4 col tiles)
        f32x4 s_acc[4];
        #pragma unroll
        for (int j = 0; j < 4; ++j) s_acc[j] = zero;
        #pragma unroll
        for (int j = 0; j < 4; ++j) {
            bf16x8 kb0 = *(const bf16x8*)(Ks + (j * 16 + l16) * 64 + quad * 8);
            bf16x8 kb1 = *(const bf16x8*)(Ks + (j * 16 + l16) * 64 + 32 + quad * 8);
            s_acc[j] = __builtin_amdgcn_mfma_f32_16x16x32_bf16(q_frag[0], kb0, s_acc[j], 0, 0, 0);
            s_acc[j] = __builtin_amdgcn_mfma_f32_16x16x32_bf16(q_frag[1], kb1, s_acc[j], 0, 0, 0);
        }

        // scale + causal mask (diagonal tile only; kt<qt tiles are fully valid)
        const float scale = 0.125f;  // 1/sqrt(64)
        if (kt == qt) {
            #pragma unroll
            for (int j = 0; j < 4; ++j)
                #pragma unroll
                for (int r = 0; r < 4; ++r) {
                    int col = kt * 64 + j * 16 + l16;
                    int row = qt * 64 + wave * 16 + quad * 4 + r;
                    s_acc[j][r] = (col <= row) ? s_acc[j][r] * scale : -INFINITY;
                }
        } else {
            #pragma unroll
            for (int j = 0; j < 4; ++j)
                #pragma unroll
                for (int r = 0; r < 4; ++r) s_acc[j][r] *= scale;
        }

        // row-wise max over 4 col tiles + 16 lanes of the quad
        float mloc[4];
        #pragma unroll
        for (int r = 0; r < 4; ++r) {
            mloc[r] = fmaxf(fmaxf(s_acc[0][r], s_acc[1][r]),
                            fmaxf(s_acc[2][r], s_acc[3][r]));
        }
        #pragma unroll
        for (int off = 1; off < 16; off <<= 1)
            #pragma unroll
            for (int r = 0; r < 4; ++r)
                mloc[r] = fmaxf(mloc[r], __shfl_xor(mloc[r], off, 64));

        float alpha[4];
        #pragma unroll
        for (int r = 0; r < 4; ++r) {
            float mn = fmaxf(m_r[r], mloc[r]);
            alpha[r] = __expf(m_r[r] - mn);   // exp(-inf)=0 on first tile
            m_r[r] = mn;
        }

        // P = exp(S - m), row sums
        float lloc[4] = {0.f, 0.f, 0.f, 0.f};
        #pragma unroll
        for (int j = 0; j < 4; ++j)
            #pragma unroll
            for (int r = 0; r < 4; ++r) {
                float p = __expf(s_acc[j][r] - m_r[r]);
                s_acc[j][r] = p;
                lloc[r] += p;
            }
        #pragma unroll
        for (int off = 1; off < 16; off <<= 1)
            #pragma unroll
            for (int r = 0; r < 4; ++r)
                lloc[r] += __shfl_xor(lloc[r], off, 64);
        #pragma unroll
        for (int r = 0; r < 4; ++r) l_r[r] = l_r[r] * alpha[r] + lloc[r];

        // write P (bf16) to LDS in [qrow][key] layout
        #pragma unroll
        for (int j = 0; j < 4; ++j)
            #pragma unroll
            for (int r = 0; r < 4; ++r)
                Ps[(wave * 16 + quad * 4 + r) * 72 + j * 16 + l16] =
                    f32_to_bf16(s_acc[j][r]);
        __syncthreads();

        // O = alpha*O + P V   (A = Ps rows, B = Vst[dim][key])
        #pragma unroll
        for (int j = 0; j < 4; ++j)
            #pragma unroll
            for (int r = 0; r < 4; ++r) o_acc[j][r] *= alpha[r];

        bf16x8 p0 = *(const bf16x8*)(Ps + (wave * 16 + l16) * 72 + quad * 8);
        bf16x8 p1 = *(const bf16x8*)(Ps + (wave * 16 + l16) * 72 + 32 + quad * 8);
        #pragma unroll
        for (int j = 0; j < 4; ++j) {
            bf16x8 vb0 = *(const bf16x8*)(Vst + (j * 16 + l16) * 72 + quad * 8);
            bf16x8 vb1 = *(const bf16x8*)(Vst + (j * 16 + l16) * 72 + 32 + quad * 8);
            o_acc[j] = __builtin_amdgcn_mfma_f32_16x16x32_bf16(p0, vb0, o_acc[j], 0, 0, 0);
            o_acc[j] = __builtin_amdgcn_mfma_f32_16x16x32_bf16(p1, vb1, o_acc[j], 0, 0, 0);
        }
        __syncthreads();  // protect Ks/Vst before next stage
    }

    // epilogue: O / l -> bf16, [B,S,E] at head column block
    #pragma unroll
    for (int j = 0; j < 4; ++j)
        #pragma unroll
        for (int r = 0; r < 4; ++r) {
            int row = qt * 64 + wave * 16 + quad * 4 + r;
            int col = j * 16 + l16;
            O[base + (size_t)row * EDIM + col] = f32_to_bf16(o_acc[j][r] / l_r[r]);
        }
}

// ---------------- launch ----------------
extern "C" void kernel_launch(void* const* d_in, const int* in_sizes, int n_in,
                              void* d_out, int out_size, void* d_ws, size_t ws_size,
                              hipStream_t stream) {
    const float* X  = (const float*)d_in[0];
    // d_in[1] = attention_mask (all true) -- causal mask subsumes it
    const float* Wq = (const float*)d_in[2];
    const float* Wk = (const float*)d_in[3];
    const float* Wv = (const float*)d_in[4];
    const float* Wp = (const float*)d_in[5];
    float* out = (float*)d_out;

    unsigned short* Xb  = (unsigned short*)d_ws;
    unsigned short* Wqb = Xb  + (size_t)MTOT * EDIM;
    unsigned short* Wkb = Wqb + (size_t)EDIM * EDIM;
    unsigned short* Wvb = Wkb + (size_t)EDIM * EDIM;
    unsigned short* Wpb = Wvb + (size_t)EDIM * EDIM;
    unsigned short* Qb  = Wpb + (size_t)EDIM * EDIM;
    unsigned short* Kb  = Qb  + (size_t)MTOT * EDIM;
    unsigned short* Vb  = Kb  + (size_t)MTOT * EDIM;
    unsigned short* Ab  = Vb  + (size_t)MTOT * EDIM;
    // total: 5*16MiB + 4*2MiB = 88 MiB of workspace

    const int nX = MTOT * EDIM;      // 8388608
    const int nW = EDIM * EDIM;      // 1048576
    cast_f32_bf16<<<nX / 1024, 256, 0, stream>>>(X,  Xb,  nX);
    cast_f32_bf16<<<nW / 1024, 256, 0, stream>>>(Wq, Wqb, nW);
    cast_f32_bf16<<<nW / 1024, 256, 0, stream>>>(Wk, Wkb, nW);
    cast_f32_bf16<<<nW / 1024, 256, 0, stream>>>(Wv, Wvb, nW);
    cast_f32_bf16<<<nW / 1024, 256, 0, stream>>>(Wp, Wpb, nW);

    dim3 gg(MTOT / 128, EDIM / 128);
    gemm_bt<unsigned short><<<gg, 256, 0, stream>>>(Xb, Wqb, Qb, MTOT, EDIM, EDIM);
    gemm_bt<unsigned short><<<gg, 256, 0, stream>>>(Xb, Wkb, Kb, MTOT, EDIM, EDIM);
    gemm_bt<unsigned short><<<gg, 256, 0, stream>>>(Xb, Wvb, Vb, MTOT, EDIM, EDIM);

    flash_attn<<<dim3(SLEN / 64, NHEAD, BATCH), 256, 0, stream>>>(Qb, Kb, Vb, Ab);

    gemm_bt<float><<<gg, 256, 0, stream>>>(Ab, Wpb, out, MTOT, EDIM, EDIM);
}

// Round 2
// 478.985 us; speedup vs baseline: 1.0865x; 1.0865x over previous
//
#include <hip/hip_runtime.h>

// Problem constants (B=4, S=2048, E=1024, H=16, D=64)
#define BATCH 4
#define SLEN  2048
#define EDIM  1024
#define NHEAD 16
#define DHEAD 64
#define MTOT  (BATCH * SLEN)   // 8192 rows

typedef float f32x4 __attribute__((ext_vector_type(4)));
typedef __bf16 bf16x8 __attribute__((ext_vector_type(8)));

#define SCALEQ 0.18033688f  // (1/sqrt(64)) * log2(e), folded into Q; flash uses exp2

__device__ __forceinline__ unsigned short f32_to_bf16(float f) {
    unsigned int u = __float_as_uint(f);
    u = (u + 0x7FFFu + ((u >> 16) & 1u)) >> 16;
    return (unsigned short)u;
}

__device__ __forceinline__ float fexp2(float x) { return __builtin_amdgcn_exp2f(x); }

__device__ __forceinline__ void gload_lds16(const void* g, void* l) {
    __builtin_amdgcn_global_load_lds(
        (const __attribute__((address_space(1))) void*)g,
        (__attribute__((address_space(3))) void*)l, 16, 0, 0);
}

// ---------------- fused fp32 -> bf16 cast of X + 4 weights ----------------
__global__ void cast_all(const float* __restrict__ X,
                         const float* __restrict__ Wq, const float* __restrict__ Wk,
                         const float* __restrict__ Wv, const float* __restrict__ Wp,
                         unsigned short* __restrict__ dst) {
    const int NX = MTOT * EDIM;     // 8388608
    const int NW = EDIM * EDIM;     // 1048576
    int idx = (blockIdx.x * blockDim.x + threadIdx.x) * 4;
    const float* src; int off;
    int t = idx - NX;
    if (idx < NX)       { src = X;  off = idx; }
    else if (t < NW)    { src = Wq; off = t; }
    else if (t < 2*NW)  { src = Wk; off = t - NW; }
    else if (t < 3*NW)  { src = Wv; off = t - 2*NW; }
    else                { src = Wp; off = t - 3*NW; }
    float4 f = *(const float4*)(src + off);
    ushort4 o;
    o.x = f32_to_bf16(f.x); o.y = f32_to_bf16(f.y);
    o.z = f32_to_bf16(f.z); o.w = f32_to_bf16(f.w);
    *(ushort4*)(dst + idx) = o;
}

// ---------------- fused QKV GEMM: [8192,1024] x [3072,1024]^T ----------------
// Epilogue routes by output column block: Q (scaled), K (plain), V (transposed
// per head into Vt[b*H+h][d][s], packed 8B stores).
__global__ __launch_bounds__(256) void gemm_qkv(
    const unsigned short* __restrict__ A,    // Xb [8192,1024]
    const unsigned short* __restrict__ Bm,   // Wcat [3072,1024]
    unsigned short* __restrict__ Qo,         // [B,S,E]
    unsigned short* __restrict__ Ko,         // [B,S,E]
    unsigned short* __restrict__ Vto)        // [B*H, D, S]
{
    __shared__ unsigned short As[128 * 32];
    __shared__ unsigned short Bs[128 * 32];
    const int K = EDIM;
    const int bm = blockIdx.x, bn = blockIdx.y;
    const int tid = threadIdx.x;
    const int wave = tid >> 6, lane = tid & 63;
    const int quad = lane >> 4, l16 = lane & 15;
    const int wm = (wave >> 1) * 64, wn = (wave & 1) * 64;

    f32x4 acc[4][4];
    const f32x4 zero = {0.f, 0.f, 0.f, 0.f};
    #pragma unroll
    for (int i = 0; i < 4; ++i)
        #pragma unroll
        for (int j = 0; j < 4; ++j) acc[i][j] = zero;

    for (int k0 = 0; k0 < K; k0 += 32) {
        #pragma unroll
        for (int c = 0; c < 2; ++c) {
            int flat = c * 2048 + tid * 8;
            int row = flat >> 5, col = flat & 31;
            gload_lds16(A + (size_t)(bm * 128 + row) * K + k0 + col, As + flat);
            gload_lds16(Bm + (size_t)(bn * 128 + row) * K + k0 + col, Bs + flat);
        }
        __syncthreads();
        bf16x8 a_frag[4], b_frag[4];
        #pragma unroll
        for (int i = 0; i < 4; ++i) {
            a_frag[i] = *(const bf16x8*)(As + (wm + i * 16 + l16) * 32 + quad * 8);
            b_frag[i] = *(const bf16x8*)(Bs + (wn + i * 16 + l16) * 32 + quad * 8);
        }
        #pragma unroll
        for (int i = 0; i < 4; ++i)
            #pragma unroll
            for (int j = 0; j < 4; ++j)
                acc[i][j] = __builtin_amdgcn_mfma_f32_16x16x32_bf16(
                    a_frag[i], b_frag[j], acc[i][j], 0, 0, 0);
        __syncthreads();
    }

    // C/D layout: col = l16, row = quad*4 + r
    #pragma unroll
    for (int i = 0; i < 4; ++i) {
        int gr = bm * 128 + wm + i * 16 + quad * 4;
        #pragma unroll
        for (int j = 0; j < 4; ++j) {
            int gc = bn * 128 + wn + j * 16 + l16;
            if (bn < 8) {          // Q, pre-scaled
                #pragma unroll
                for (int r = 0; r < 4; ++r)
                    Qo[(size_t)(gr + r) * EDIM + gc] = f32_to_bf16(acc[i][j][r] * SCALEQ);
            } else if (bn < 16) {  // K
                int c = gc - 1024;
                #pragma unroll
                for (int r = 0; r < 4; ++r)
                    Ko[(size_t)(gr + r) * EDIM + c] = f32_to_bf16(acc[i][j][r]);
            } else {               // V -> transposed per head
                int e = gc - 2048;
                int hh = e >> 6, d = e & 63;
                int bb = gr >> 11, s = gr & 2047;
                ushort4 pk;
                pk.x = f32_to_bf16(acc[i][j][0]); pk.y = f32_to_bf16(acc[i][j][1]);
                pk.z = f32_to_bf16(acc[i][j][2]); pk.w = f32_to_bf16(acc[i][j][3]);
                *(ushort4*)(Vto + ((size_t)(bb * NHEAD + hh) * DHEAD + d) * SLEN + s) = pk;
            }
        }
    }
}

// ---------------- generic A*B^T GEMM, fp32 out (output projection) ----------
__global__ __launch_bounds__(256) void gemm_bt_f32(
    const unsigned short* __restrict__ A,
    const unsigned short* __restrict__ Bm,
    float* __restrict__ C, int M, int N, int K)
{
    __shared__ unsigned short As[128 * 32];
    __shared__ unsigned short Bs[128 * 32];
    const int bm = blockIdx.x, bn = blockIdx.y;
    const int tid = threadIdx.x;
    const int wave = tid >> 6, lane = tid & 63;
    const int quad = lane >> 4, l16 = lane & 15;
    const int wm = (wave >> 1) * 64, wn = (wave & 1) * 64;

    f32x4 acc[4][4];
    const f32x4 zero = {0.f, 0.f, 0.f, 0.f};
    #pragma unroll
    for (int i = 0; i < 4; ++i)
        #pragma unroll
        for (int j = 0; j < 4; ++j) acc[i][j] = zero;

    for (int k0 = 0; k0 < K; k0 += 32) {
        #pragma unroll
        for (int c = 0; c < 2; ++c) {
            int flat = c * 2048 + tid * 8;
            int row = flat >> 5, col = flat & 31;
            gload_lds16(A + (size_t)(bm * 128 + row) * K + k0 + col, As + flat);
            gload_lds16(Bm + (size_t)(bn * 128 + row) * K + k0 + col, Bs + flat);
        }
        __syncthreads();
        bf16x8 a_frag[4], b_frag[4];
        #pragma unroll
        for (int i = 0; i < 4; ++i) {
            a_frag[i] = *(const bf16x8*)(As + (wm + i * 16 + l16) * 32 + quad * 8);
            b_frag[i] = *(const bf16x8*)(Bs + (wn + i * 16 + l16) * 32 + quad * 8);
        }
        #pragma unroll
        for (int i = 0; i < 4; ++i)
            #pragma unroll
            for (int j = 0; j < 4; ++j)
                acc[i][j] = __builtin_amdgcn_mfma_f32_16x16x32_bf16(
                    a_frag[i], b_frag[j], acc[i][j], 0, 0, 0);
        __syncthreads();
    }
    #pragma unroll
    for (int i = 0; i < 4; ++i) {
        int row = bm * 128 + wm + i * 16 + quad * 4;
        #pragma unroll
        for (int j = 0; j < 4; ++j) {
            int col = bn * 128 + wn + j * 16 + l16;
            #pragma unroll
            for (int r = 0; r < 4; ++r)
                C[(size_t)(row + r) * N + col] = acc[i][j][r];
        }
    }
}

// ---------------- flash causal attention v2: barrier-free ----------------
// grid (16, 16, 4) = 1024 blocks, 256 thr (4 waves). Each wave independently
// owns 32 q rows; K/V fragments loaded straight from global (L1/L2 cached);
// only the wave-private P transpose goes through LDS. No __syncthreads.
__global__ __launch_bounds__(256, 4) void flash_attn2(
    const unsigned short* __restrict__ Q,   // [B,S,E] bf16, pre-scaled
    const unsigned short* __restrict__ K,   // [B,S,E] bf16
    const unsigned short* __restrict__ Vt,  // [B*H, D, S] bf16
    unsigned short* __restrict__ O)         // [B,S,E] bf16
{
    const int qt = gridDim.x - 1 - blockIdx.x;   // heavy blocks first
    const int h = blockIdx.y, b = blockIdx.z;
    const int tid = threadIdx.x;
    const int wave = tid >> 6, lane = tid & 63;
    const int quad = lane >> 4, l16 = lane & 15;

    __shared__ unsigned short Ps[4 * 32 * 72];
    unsigned short* Pw = Ps + wave * 32 * 72;     // wave-private

    const size_t qkb = (size_t)b * SLEN * EDIM + h * DHEAD;
    const size_t vtb = (size_t)(b * NHEAD + h) * DHEAD * SLEN;
    const int qbase = qt * 128 + wave * 32;

    // Q fragments: A[m=l16][k=kh*32+quad*8+j]
    bf16x8 qf[2][2];
    #pragma unroll
    for (int mt = 0; mt < 2; ++mt) {
        const unsigned short* qp =
            Q + qkb + (size_t)(qbase + mt * 16 + l16) * EDIM + quad * 8;
        qf[mt][0] = *(const bf16x8*)qp;
        qf[mt][1] = *(const bf16x8*)(qp + 32);
    }

    const f32x4 zero = {0.f, 0.f, 0.f, 0.f};
    f32x4 o_acc[2][4];
    float m_r[2][4], l_r[2][4];
    #pragma unroll
    for (int mt = 0; mt < 2; ++mt) {
        #pragma unroll
        for (int j = 0; j < 4; ++j) o_acc[mt][j] = zero;
        #pragma unroll
        for (int r = 0; r < 4; ++r) { m_r[mt][r] = -INFINITY; l_r[mt][r] = 0.f; }
    }

    const int dtile = qbase >> 6;
    for (int kt = 0; kt <= dtile; ++kt) {
        // ---- S = Q K^T (32 q rows x 64 keys) ----
        f32x4 s[2][4];
        #pragma unroll
        for (int mt = 0; mt < 2; ++mt)
            #pragma unroll
            for (int j = 0; j < 4; ++j) s[mt][j] = zero;
        #pragma unroll
        for (int j = 0; j < 4; ++j) {
            const unsigned short* kp =
                K + qkb + (size_t)(kt * 64 + j * 16 + l16) * EDIM + quad * 8;
            bf16x8 k0 = *(const bf16x8*)kp;
            bf16x8 k1 = *(const bf16x8*)(kp + 32);
            s[0][j] = __builtin_amdgcn_mfma_f32_16x16x32_bf16(qf[0][0], k0, s[0][j], 0, 0, 0);
            s[1][j] = __builtin_amdgcn_mfma_f32_16x16x32_bf16(qf[1][0], k0, s[1][j], 0, 0, 0);
            s[0][j] = __builtin_amdgcn_mfma_f32_16x16x32_bf16(qf[0][1], k1, s[0][j], 0, 0, 0);
            s[1][j] = __builtin_amdgcn_mfma_f32_16x16x32_bf16(qf[1][1], k1, s[1][j], 0, 0, 0);
        }

        // ---- causal mask on diagonal tile only ----
        if (kt == dtile) {
            #pragma unroll
            for (int mt = 0; mt < 2; ++mt)
                #pragma unroll
                for (int j = 0; j < 4; ++j) {
                    int col = kt * 64 + j * 16 + l16;
                    #pragma unroll
                    for (int r = 0; r < 4; ++r) {
                        int row = qbase + mt * 16 + quad * 4 + r;
                        if (col > row) s[mt][j][r] = -INFINITY;
                    }
                }
        }

        // ---- online softmax (base-2; scale folded into Q) ----
        #pragma unroll
        for (int mt = 0; mt < 2; ++mt) {
            float mloc[4];
            #pragma unroll
            for (int r = 0; r < 4; ++r)
                mloc[r] = fmaxf(fmaxf(s[mt][0][r], s[mt][1][r]),
                                fmaxf(s[mt][2][r], s[mt][3][r]));
            #pragma unroll
            for (int off = 1; off < 16; off <<= 1)
                #pragma unroll
                for (int r = 0; r < 4; ++r)
                    mloc[r] = fmaxf(mloc[r], __shfl_xor(mloc[r], off, 64));
            float alpha[4];
            #pragma unroll
            for (int r = 0; r < 4; ++r) {
                float mn = fmaxf(m_r[mt][r], mloc[r]);
                alpha[r] = fexp2(m_r[mt][r] - mn);
                m_r[mt][r] = mn;
            }
            float lloc[4] = {0.f, 0.f, 0.f, 0.f};
            #pragma unroll
            for (int j = 0; j < 4; ++j)
                #pragma unroll
                for (int r = 0; r < 4; ++r) {
                    float p = fexp2(s[mt][j][r] - m_r[mt][r]);
                    lloc[r] += p;
                    Pw[(mt * 16 + quad * 4 + r) * 72 + j * 16 + l16] = f32_to_bf16(p);
                }
            #pragma unroll
            for (int off = 1; off < 16; off <<= 1)
                #pragma unroll
                for (int r = 0; r < 4; ++r)
                    lloc[r] += __shfl_xor(lloc[r], off, 64);
            #pragma unroll
            for (int r = 0; r < 4; ++r) {
                l_r[mt][r] = l_r[mt][r] * alpha[r] + lloc[r];
                o_acc[mt][0][r] *= alpha[r];
                o_acc[mt][1][r] *= alpha[r];
                o_acc[mt][2][r] *= alpha[r];
                o_acc[mt][3][r] *= alpha[r];
            }
        }

        // ---- O += P V  (A = wave-private Ps, B = Vt rows from global) ----
        bf16x8 pa[2][2];
        #pragma unroll
        for (int mt = 0; mt < 2; ++mt) {
            pa[mt][0] = *(const bf16x8*)(Pw + (mt * 16 + l16) * 72 + quad * 8);
            pa[mt][1] = *(const bf16x8*)(Pw + (mt * 16 + l16) * 72 + 32 + quad * 8);
        }
        #pragma unroll
        for (int j = 0; j < 4; ++j) {
            const unsigned short* vp =
                Vt + vtb + (size_t)(j * 16 + l16) * SLEN + kt * 64 + quad * 8;
            bf16x8 v0 = *(const bf16x8*)vp;
            bf16x8 v1 = *(const bf16x8*)(vp + 32);
            o_acc[0][j] = __builtin_amdgcn_mfma_f32_16x16x32_bf16(pa[0][0], v0, o_acc[0][j], 0, 0, 0);
            o_acc[1][j] = __builtin_amdgcn_mfma_f32_16x16x32_bf16(pa[1][0], v0, o_acc[1][j], 0, 0, 0);
            o_acc[0][j] = __builtin_amdgcn_mfma_f32_16x16x32_bf16(pa[0][1], v1, o_acc[0][j], 0, 0, 0);
            o_acc[1][j] = __builtin_amdgcn_mfma_f32_16x16x32_bf16(pa[1][1], v1, o_acc[1][j], 0, 0, 0);
        }
    }

    // ---- epilogue: O / l ----
    #pragma unroll
    for (int mt = 0; mt < 2; ++mt)
        #pragma unroll
        for (int j = 0; j < 4; ++j)
            #pragma unroll
            for (int r = 0; r < 4; ++r) {
                int row = qbase + mt * 16 + quad * 4 + r;
                O[qkb + (size_t)row * EDIM + j * 16 + l16] =
                    f32_to_bf16(o_acc[mt][j][r] / l_r[mt][r]);
            }
}

// ---------------- launch ----------------
extern "C" void kernel_launch(void* const* d_in, const int* in_sizes, int n_in,
                              void* d_out, int out_size, void* d_ws, size_t ws_size,
                              hipStream_t stream) {
    const float* X  = (const float*)d_in[0];
    // d_in[1] = attention_mask (all true) -- causal mask subsumes it
    const float* Wq = (const float*)d_in[2];
    const float* Wk = (const float*)d_in[3];
    const float* Wv = (const float*)d_in[4];
    const float* Wp = (const float*)d_in[5];
    float* out = (float*)d_out;

    const size_t NX = (size_t)MTOT * EDIM;   // 8388608
    const size_t NW = (size_t)EDIM * EDIM;   // 1048576
    unsigned short* Xb  = (unsigned short*)d_ws;
    unsigned short* Wqb = Xb  + NX;          // Wq,Wk,Wv contiguous = Wcat[3072,1024]
    unsigned short* Wpb = Wqb + 3 * NW;
    unsigned short* Qb  = Wpb + NW;
    unsigned short* Kb  = Qb  + NX;
    unsigned short* Vtb = Kb  + NX;
    unsigned short* Ab  = Vtb + NX;
    // total ~75.5 MiB

    cast_all<<<(NX + 4 * NW) / 1024, 256, 0, stream>>>(X, Wq, Wk, Wv, Wp, Xb);

    gemm_qkv<<<dim3(MTOT / 128, 3 * EDIM / 128), 256, 0, stream>>>(
        Xb, Wqb, Qb, Kb, Vtb);

    flash_attn2<<<dim3(SLEN / 128, NHEAD, BATCH), 256, 0, stream>>>(Qb, Kb, Vtb, Ab);

    gemm_bt_f32<<<dim3(MTOT / 128, EDIM / 128), 256, 0, stream>>>(
        Ab, Wpb, out, MTOT, EDIM, EDIM);
}

// Round 3
// 384.740 us; speedup vs baseline: 1.3526x; 1.2450x over previous
//
#include <hip/hip_runtime.h>

// Problem constants (B=4, S=2048, E=1024, H=16, D=64)
#define BATCH 4
#define SLEN  2048
#define EDIM  1024
#define NHEAD 16
#define DHEAD 64
#define MTOT  (BATCH * SLEN)   // 8192 rows

typedef float f32x4 __attribute__((ext_vector_type(4)));
typedef __bf16 bf16x8 __attribute__((ext_vector_type(8)));

#define SCALEQ 0.18033688f  // (1/sqrt(64)) * log2(e); flash uses exp2

__device__ __forceinline__ unsigned short f32_to_bf16(float f) {
    unsigned int u = __float_as_uint(f);
    u = (u + 0x7FFFu + ((u >> 16) & 1u)) >> 16;
    return (unsigned short)u;
}

// pack two f32 -> bf16x2 dword (round-half-up), lo in low half
__device__ __forceinline__ unsigned int pack_bf16(float lo, float hi) {
    unsigned int a = __float_as_uint(lo) + 0x8000u;
    unsigned int b = __float_as_uint(hi) + 0x8000u;
    return __builtin_amdgcn_perm(b, a, 0x07060302);  // [b.hi16 : a.hi16]
}

__device__ __forceinline__ float fexp2(float x) { return __builtin_amdgcn_exp2f(x); }

__device__ __forceinline__ void gload_lds16(const void* g, void* l) {
    __builtin_amdgcn_global_load_lds(
        (const __attribute__((address_space(1))) void*)g,
        (__attribute__((address_space(3))) void*)l, 16, 0, 0);
}

// ---------------- fused fp32 -> bf16 cast of X + 4 weights ----------------
__global__ void cast_all(const float* __restrict__ X,
                         const float* __restrict__ Wq, const float* __restrict__ Wk,
                         const float* __restrict__ Wv, const float* __restrict__ Wp,
                         unsigned short* __restrict__ dst) {
    const int NX = MTOT * EDIM;
    const int NW = EDIM * EDIM;
    int idx = (blockIdx.x * blockDim.x + threadIdx.x) * 4;
    const float* src; int off;
    int t = idx - NX;
    if (idx < NX)       { src = X;  off = idx; }
    else if (t < NW)    { src = Wq; off = t; }
    else if (t < 2*NW)  { src = Wk; off = t - NW; }
    else if (t < 3*NW)  { src = Wv; off = t - 2*NW; }
    else                { src = Wp; off = t - 3*NW; }
    float4 f = *(const float4*)(src + off);
    ushort4 o;
    o.x = f32_to_bf16(f.x); o.y = f32_to_bf16(f.y);
    o.z = f32_to_bf16(f.z); o.w = f32_to_bf16(f.w);
    *(ushort4*)(dst + idx) = o;
}

// ---------------- fused QKV GEMM: [8192,1024] x [3072,1024]^T ----------------
__global__ __launch_bounds__(256) void gemm_qkv(
    const unsigned short* __restrict__ A,    // Xb [8192,1024]
    const unsigned short* __restrict__ Bm,   // Wcat [3072,1024]
    unsigned short* __restrict__ Qo,         // [B,S,E], pre-scaled by SCALEQ
    unsigned short* __restrict__ Ko,         // [B,S,E]
    unsigned short* __restrict__ Vto)        // [B*H, D, S]
{
    __shared__ unsigned short As[128 * 32];
    __shared__ unsigned short Bs[128 * 32];
    const int K = EDIM;
    const int bm = blockIdx.x, bn = blockIdx.y;
    const int tid = threadIdx.x;
    const int wave = tid >> 6, lane = tid & 63;
    const int quad = lane >> 4, l16 = lane & 15;
    const int wm = (wave >> 1) * 64, wn = (wave & 1) * 64;

    f32x4 acc[4][4];
    const f32x4 zero = {0.f, 0.f, 0.f, 0.f};
    #pragma unroll
    for (int i = 0; i < 4; ++i)
        #pragma unroll
        for (int j = 0; j < 4; ++j) acc[i][j] = zero;

    for (int k0 = 0; k0 < K; k0 += 32) {
        #pragma unroll
        for (int c = 0; c < 2; ++c) {
            int flat = c * 2048 + tid * 8;
            int row = flat >> 5, col = flat & 31;
            gload_lds16(A + (size_t)(bm * 128 + row) * K + k0 + col, As + flat);
            gload_lds16(Bm + (size_t)(bn * 128 + row) * K + k0 + col, Bs + flat);
        }
        __syncthreads();
        bf16x8 a_frag[4], b_frag[4];
        #pragma unroll
        for (int i = 0; i < 4; ++i) {
            a_frag[i] = *(const bf16x8*)(As + (wm + i * 16 + l16) * 32 + quad * 8);
            b_frag[i] = *(const bf16x8*)(Bs + (wn + i * 16 + l16) * 32 + quad * 8);
        }
        #pragma unroll
        for (int i = 0; i < 4; ++i)
            #pragma unroll
            for (int j = 0; j < 4; ++j)
                acc[i][j] = __builtin_amdgcn_mfma_f32_16x16x32_bf16(
                    a_frag[i], b_frag[j], acc[i][j], 0, 0, 0);
        __syncthreads();
    }

    #pragma unroll
    for (int i = 0; i < 4; ++i) {
        int gr = bm * 128 + wm + i * 16 + quad * 4;
        #pragma unroll
        for (int j = 0; j < 4; ++j) {
            int gc = bn * 128 + wn + j * 16 + l16;
            if (bn < 8) {          // Q, pre-scaled
                #pragma unroll
                for (int r = 0; r < 4; ++r)
                    Qo[(size_t)(gr + r) * EDIM + gc] = f32_to_bf16(acc[i][j][r] * SCALEQ);
            } else if (bn < 16) {  // K
                int c = gc - 1024;
                #pragma unroll
                for (int r = 0; r < 4; ++r)
                    Ko[(size_t)(gr + r) * EDIM + c] = f32_to_bf16(acc[i][j][r]);
            } else {               // V -> transposed per head
                int e = gc - 2048;
                int hh = e >> 6, d = e & 63;
                int bb = gr >> 11, s = gr & 2047;
                ushort4 pk;
                pk.x = f32_to_bf16(acc[i][j][0]); pk.y = f32_to_bf16(acc[i][j][1]);
                pk.z = f32_to_bf16(acc[i][j][2]); pk.w = f32_to_bf16(acc[i][j][3]);
                *(ushort4*)(Vto + ((size_t)(bb * NHEAD + hh) * DHEAD + d) * SLEN + s) = pk;
            }
        }
    }
}

// ---------------- generic A*B^T GEMM, fp32 out (output projection) ----------
__global__ __launch_bounds__(256) void gemm_bt_f32(
    const unsigned short* __restrict__ A,
    const unsigned short* __restrict__ Bm,
    float* __restrict__ C, int M, int N, int K)
{
    __shared__ unsigned short As[128 * 32];
    __shared__ unsigned short Bs[128 * 32];
    const int bm = blockIdx.x, bn = blockIdx.y;
    const int tid = threadIdx.x;
    const int wave = tid >> 6, lane = tid & 63;
    const int quad = lane >> 4, l16 = lane & 15;
    const int wm = (wave >> 1) * 64, wn = (wave & 1) * 64;

    f32x4 acc[4][4];
    const f32x4 zero = {0.f, 0.f, 0.f, 0.f};
    #pragma unroll
    for (int i = 0; i < 4; ++i)
        #pragma unroll
        for (int j = 0; j < 4; ++j) acc[i][j] = zero;

    for (int k0 = 0; k0 < K; k0 += 32) {
        #pragma unroll
        for (int c = 0; c < 2; ++c) {
            int flat = c * 2048 + tid * 8;
            int row = flat >> 5, col = flat & 31;
            gload_lds16(A + (size_t)(bm * 128 + row) * K + k0 + col, As + flat);
            gload_lds16(Bm + (size_t)(bn * 128 + row) * K + k0 + col, Bs + flat);
        }
        __syncthreads();
        bf16x8 a_frag[4], b_frag[4];
        #pragma unroll
        for (int i = 0; i < 4; ++i) {
            a_frag[i] = *(const bf16x8*)(As + (wm + i * 16 + l16) * 32 + quad * 8);
            b_frag[i] = *(const bf16x8*)(Bs + (wn + i * 16 + l16) * 32 + quad * 8);
        }
        #pragma unroll
        for (int i = 0; i < 4; ++i)
            #pragma unroll
            for (int j = 0; j < 4; ++j)
                acc[i][j] = __builtin_amdgcn_mfma_f32_16x16x32_bf16(
                    a_frag[i], b_frag[j], acc[i][j], 0, 0, 0);
        __syncthreads();
    }
    #pragma unroll
    for (int i = 0; i < 4; ++i) {
        int row = bm * 128 + wm + i * 16 + quad * 4;
        #pragma unroll
        for (int j = 0; j < 4; ++j) {
            int col = bn * 128 + wn + j * 16 + l16;
            #pragma unroll
            for (int r = 0; r < 4; ++r)
                C[(size_t)(row + r) * N + col] = acc[i][j][r];
        }
    }
}

// ---------------- flash causal attention v3: S^T layout ----------------
// Compute S^T = K Q^T so q-rows land in lane&15: softmax reductions are
// in-lane + 2 shfl_xor rounds; m/l/alpha are per-lane scalars; P stores are
// ds_write_b64. Grid (bh=64 fast, qt=32), 128-thr blocks, wave = 32 q rows.
__global__ __launch_bounds__(128, 3) void flash_attn3(
    const unsigned short* __restrict__ Q,   // [B,S,E] bf16, pre-scaled
    const unsigned short* __restrict__ K,   // [B,S,E] bf16
    const unsigned short* __restrict__ Vt,  // [B*H, D, S] bf16
    unsigned short* __restrict__ O)         // [B,S,E] bf16
{
    const int bh = blockIdx.x;                 // fast dim: balance across CUs
    const int b = bh >> 4, h = bh & 15;
    const int qt = gridDim.y - 1 - blockIdx.y; // heavy tiles dispatch last-reversed
    const int tid = threadIdx.x;
    const int wave = tid >> 6, lane = tid & 63;
    const int quad = lane >> 4, l16 = lane & 15;

    __shared__ unsigned short Ps[2 * 32 * 72];
    unsigned short* Pw = Ps + wave * 32 * 72;  // wave-private, no barriers

    const size_t qkb = (size_t)b * SLEN * EDIM + h * DHEAD;
    const size_t vtb = (size_t)(b * NHEAD + h) * DHEAD * SLEN;
    const int qb = qt * 64 + wave * 32;

    // Q fragments as B-operand: B[n = qrow = l16][k = dim = quad*8+j]
    bf16x8 qf[2][2];
    #pragma unroll
    for (int mt = 0; mt < 2; ++mt) {
        const unsigned short* qp =
            Q + qkb + (size_t)(qb + mt * 16 + l16) * EDIM + quad * 8;
        qf[mt][0] = *(const bf16x8*)qp;
        qf[mt][1] = *(const bf16x8*)(qp + 32);
    }

    const f32x4 zero = {0.f, 0.f, 0.f, 0.f};
    f32x4 o_acc[2][4];
    #pragma unroll
    for (int mt = 0; mt < 2; ++mt)
        #pragma unroll
        for (int n = 0; n < 4; ++n) o_acc[mt][n] = zero;
    float m_r[2] = {-INFINITY, -INFINITY};
    float l_r[2] = {0.f, 0.f};

    for (int kt = 0; kt <= qt; ++kt) {
        // ---- S^T = K Q^T : st[mt][t][r] = S[key = kt*64+t*16+quad*4+r][qrow = l16]
        f32x4 st[2][4];
        #pragma unroll
        for (int mt = 0; mt < 2; ++mt)
            #pragma unroll
            for (int t = 0; t < 4; ++t) st[mt][t] = zero;
        #pragma unroll
        for (int t = 0; t < 4; ++t) {
            const unsigned short* kp =
                K + qkb + (size_t)(kt * 64 + t * 16 + l16) * EDIM + quad * 8;
            bf16x8 k0 = *(const bf16x8*)kp;
            bf16x8 k1 = *(const bf16x8*)(kp + 32);
            st[0][t] = __builtin_amdgcn_mfma_f32_16x16x32_bf16(k0, qf[0][0], st[0][t], 0, 0, 0);
            st[1][t] = __builtin_amdgcn_mfma_f32_16x16x32_bf16(k0, qf[1][0], st[1][t], 0, 0, 0);
            st[0][t] = __builtin_amdgcn_mfma_f32_16x16x32_bf16(k1, qf[0][1], st[0][t], 0, 0, 0);
            st[1][t] = __builtin_amdgcn_mfma_f32_16x16x32_bf16(k1, qf[1][1], st[1][t], 0, 0, 0);
        }

        // ---- causal mask (diagonal tile only; per-lane arithmetic)
        if (kt == qt) {
            #pragma unroll
            for (int mt = 0; mt < 2; ++mt) {
                int row = qb + mt * 16 + l16;
                #pragma unroll
                for (int t = 0; t < 4; ++t)
                    #pragma unroll
                    for (int r = 0; r < 4; ++r) {
                        int key = kt * 64 + t * 16 + quad * 4 + r;
                        if (key > row) st[mt][t][r] = -INFINITY;
                    }
            }
        }

        // ---- online softmax: in-lane + 2 cross-quad shfl rounds
        #pragma unroll
        for (int mt = 0; mt < 2; ++mt) {
            float mx = st[mt][0][0];
            #pragma unroll
            for (int t = 0; t < 4; ++t)
                #pragma unroll
                for (int r = 0; r < 4; ++r) mx = fmaxf(mx, st[mt][t][r]);
            mx = fmaxf(mx, __shfl_xor(mx, 16, 64));
            mx = fmaxf(mx, __shfl_xor(mx, 32, 64));
            float mn = fmaxf(m_r[mt], mx);
            float alpha = fexp2(m_r[mt] - mn);
            m_r[mt] = mn;

            float ls0 = 0.f, ls1 = 0.f, ls2 = 0.f, ls3 = 0.f;
            #pragma unroll
            for (int t = 0; t < 4; ++t) {
                float p0 = fexp2(st[mt][t][0] - mn);
                float p1 = fexp2(st[mt][t][1] - mn);
                float p2 = fexp2(st[mt][t][2] - mn);
                float p3 = fexp2(st[mt][t][3] - mn);
                ls0 += p0; ls1 += p1; ls2 += p2; ls3 += p3;
                uint2 pk;
                pk.x = pack_bf16(p0, p1);
                pk.y = pack_bf16(p2, p3);
                // row (mt*16+l16), keys t*16+quad*4 .. +3 -> 8B vector write
                *(uint2*)(Pw + (mt * 16 + l16) * 72 + t * 16 + quad * 4) = pk;
            }
            float ls = (ls0 + ls1) + (ls2 + ls3);
            ls += __shfl_xor(ls, 16, 64);
            ls += __shfl_xor(ls, 32, 64);
            l_r[mt] = l_r[mt] * alpha + ls;

            // rescale O rows (rows quad*4+r; alpha lives in lane quad*4+r)
            #pragma unroll
            for (int r = 0; r < 4; ++r) {
                float a = __shfl(alpha, quad * 4 + r, 64);
                o_acc[mt][0][r] *= a; o_acc[mt][1][r] *= a;
                o_acc[mt][2][r] *= a; o_acc[mt][3][r] *= a;
            }
        }

        // ---- O += P V : A = Pw rows (m=qrow), B = Vt rows (n=dim)
        bf16x8 pa[2][2];
        #pragma unroll
        for (int mt = 0; mt < 2; ++mt) {
            pa[mt][0] = *(const bf16x8*)(Pw + (mt * 16 + l16) * 72 + quad * 8);
            pa[mt][1] = *(const bf16x8*)(Pw + (mt * 16 + l16) * 72 + 32 + quad * 8);
        }
        #pragma unroll
        for (int n = 0; n < 4; ++n) {
            const unsigned short* vp =
                Vt + vtb + (size_t)(n * 16 + l16) * SLEN + kt * 64 + quad * 8;
            bf16x8 v0 = *(const bf16x8*)vp;
            bf16x8 v1 = *(const bf16x8*)(vp + 32);
            o_acc[0][n] = __builtin_amdgcn_mfma_f32_16x16x32_bf16(pa[0][0], v0, o_acc[0][n], 0, 0, 0);
            o_acc[1][n] = __builtin_amdgcn_mfma_f32_16x16x32_bf16(pa[1][0], v0, o_acc[1][n], 0, 0, 0);
            o_acc[0][n] = __builtin_amdgcn_mfma_f32_16x16x32_bf16(pa[0][1], v1, o_acc[0][n], 0, 0, 0);
            o_acc[1][n] = __builtin_amdgcn_mfma_f32_16x16x32_bf16(pa[1][1], v1, o_acc[1][n], 0, 0, 0);
        }
    }

    // ---- epilogue: O / l (l lives in lane quad*4+r of each mt group)
    #pragma unroll
    for (int mt = 0; mt < 2; ++mt) {
        float inv[4];
        #pragma unroll
        for (int r = 0; r < 4; ++r)
            inv[r] = 1.0f / __shfl(l_r[mt], quad * 4 + r, 64);
        #pragma unroll
        for (int n = 0; n < 4; ++n)
            #pragma unroll
            for (int r = 0; r < 4; ++r) {
                int row = qb + mt * 16 + quad * 4 + r;
                O[qkb + (size_t)row * EDIM + n * 16 + l16] =
                    f32_to_bf16(o_acc[mt][n][r] * inv[r]);
            }
    }
}

// ---------------- launch ----------------
extern "C" void kernel_launch(void* const* d_in, const int* in_sizes, int n_in,
                              void* d_out, int out_size, void* d_ws, size_t ws_size,
                              hipStream_t stream) {
    const float* X  = (const float*)d_in[0];
    // d_in[1] = attention_mask (all true) -- causal mask subsumes it
    const float* Wq = (const float*)d_in[2];
    const float* Wk = (const float*)d_in[3];
    const float* Wv = (const float*)d_in[4];
    const float* Wp = (const float*)d_in[5];
    float* out = (float*)d_out;

    const size_t NX = (size_t)MTOT * EDIM;
    const size_t NW = (size_t)EDIM * EDIM;
    unsigned short* Xb  = (unsigned short*)d_ws;
    unsigned short* Wqb = Xb  + NX;          // Wq,Wk,Wv contiguous = Wcat[3072,1024]
    unsigned short* Wpb = Wqb + 3 * NW;
    unsigned short* Qb  = Wpb + NW;
    unsigned short* Kb  = Qb  + NX;
    unsigned short* Vtb = Kb  + NX;
    unsigned short* Ab  = Vtb + NX;

    cast_all<<<(NX + 4 * NW) / 1024, 256, 0, stream>>>(X, Wq, Wk, Wv, Wp, Xb);

    gemm_qkv<<<dim3(MTOT / 128, 3 * EDIM / 128), 256, 0, stream>>>(
        Xb, Wqb, Qb, Kb, Vtb);

    flash_attn3<<<dim3(NHEAD * BATCH, SLEN / 64), 128, 0, stream>>>(Qb, Kb, Vtb, Ab);

    gemm_bt_f32<<<dim3(MTOT / 128, EDIM / 128), 256, 0, stream>>>(
        Ab, Wpb, out, MTOT, EDIM, EDIM);
}